// Round 11
// baseline (251.127 us; speedup 1.0000x reference)
//
#include <hip/hip_runtime.h>
#include <hip/hip_bf16.h>

// WeightedLoss round 11: PACKED FRAGMENT LAYOUT, no LDS, no barriers.
// Every block of an X·X^T gram uses the identical MFMA fragment pattern, so
// prep writes Ob/Ln directly in fragment order: 16-B slot S=(g*(K/8)+o)*16+r
// holds X[g*16+r][o*8..o*8+7]. A wave's fragment load is base16+lane ->
// one coalesced 1024-B dwordx4 per fragment, straight from global (L1/L2
// lines fully used). This removes rounds 8-10's stage->vmcnt(0)->compute
// serialization AND rounds 2-7's 8x cache-line over-read; the unrolled
// K-loop pipelines 8 loads + 16 MFMAs per step with no sync points.
// ws: [0] Obp bf16 packed 4 MB | [4194304] Lnp bf16 packed 2 MB
//     [6291456] sq f32 | [6324224] pos_sums | [6356992] neg_sums
//     [6389760] stats u32[3]

#define B_N 8192
#define NT   64
#define TILE 128
#define NTRI 2080

typedef __attribute__((ext_vector_type(8))) short bf16x8;
typedef __attribute__((ext_vector_type(4))) float f32x4;
typedef __attribute__((ext_vector_type(2))) _Float16 f16x2;

__device__ __forceinline__ unsigned fenc(float f) {
    unsigned u = __float_as_uint(f);
    return (u & 0x80000000u) ? ~u : (u | 0x80000000u);
}
__device__ __forceinline__ float fdec(unsigned k) {
    unsigned u = (k & 0x80000000u) ? (k ^ 0x80000000u) : ~k;
    return __uint_as_float(u);
}
__device__ __forceinline__ unsigned pack2(float a, float b) {
    f16x2 p; p[0] = (_Float16)a; p[1] = (_Float16)b;
    return *(unsigned*)&p;
}

// XCD-swizzled upper-tri decode.
__device__ __forceinline__ void tri_decode_swz(int b, int& bi, int& bj) {
    int t = (b & 7) * (NTRI / 8) + (b >> 3);
    int i = 0, rem = t;
    while (rem >= NT - i) { rem -= NT - i; i++; }
    bi = i; bj = i + rem;
}

// ---------------------------------------------------------------- prep ----
// 4 rows/block (one wave per row). Computes sq, normalizes labels, and
// writes both matrices in PACKED fragment order (see header).
__global__ __launch_bounds__(256) void prep_kernel(
    const float* __restrict__ outputs, const float* __restrict__ labels,
    __hip_bfloat16* __restrict__ Obp, __hip_bfloat16* __restrict__ Lnp,
    float* __restrict__ sq, float* __restrict__ pos_sums,
    float* __restrict__ neg_sums, unsigned* __restrict__ stats) {
    int w = threadIdx.x >> 6, lane = threadIdx.x & 63;
    int r = blockIdx.x * 4 + w;
    int g = r >> 4, rr = r & 15;

    // outputs row: 256 f32, 4 per lane
    f32x4 v = ((const f32x4*)outputs)[r * 64 + lane];
    float s = v[0]*v[0] + v[1]*v[1] + v[2]*v[2] + v[3]*v[3];
    #pragma unroll
    for (int m = 1; m < 64; m <<= 1) s += __shfl_xor(s, m);
    if (lane == 0) { sq[r] = s; pos_sums[r] = 0.f; neg_sums[r] = 0.f; }
    __hip_bfloat16 o4[4];
    #pragma unroll
    for (int i = 0; i < 4; i++) o4[i] = __float2bfloat16(v[i]);
    {   // elems 4*lane..4*lane+3 -> octet o=lane>>1, pos=4*(lane&1); K/8=32
        int o = lane >> 1, pos = 4 * (lane & 1);
        size_t S = ((size_t)g * 32 + o) * 16 + rr;
        *(uint2*)&Obp[S * 8 + pos] = *(uint2*)o4;
    }

    // labels row: 128 f32, 2 per lane
    float2 lv = ((const float2*)labels)[r * 64 + lane];
    float ls = lv.x * lv.x + lv.y * lv.y;
    #pragma unroll
    for (int m = 1; m < 64; m <<= 1) ls += __shfl_xor(ls, m);
    float nrm = sqrtf(ls) + 1e-12f;
    __hip_bfloat16 l2[2] = { __float2bfloat16(lv.x / nrm),
                             __float2bfloat16(lv.y / nrm) };
    {   // elems 2*lane..2*lane+1 -> octet o=lane>>2, pos=2*(lane&3); K/8=16
        int o = lane >> 2, pos = 2 * (lane & 3);
        size_t S = ((size_t)g * 16 + o) * 16 + rr;
        *(unsigned*)&Lnp[S * 8 + pos] = *(unsigned*)l2;
    }

    if (blockIdx.x == 0 && threadIdx.x == 0) {
        stats[0] = 0xFFFFFFFFu; stats[1] = 0u; stats[2] = 0u;
    }
}

// ------------------------------------ packed direct-global 64x64 gram ----
// KD8 = K/8 (16 for Ln, 32 for Ob). Fragment for (mi,kc): 16-B slot
// (rb16+mi)*KD8*16 + kc*64 + lane  -> coalesced 1 KB per wave instruction.
template<int KD8>
__device__ __forceinline__ void gram_packed(
    const short* __restrict__ P, int rb16, int cb16, int lane,
    f32x4 (&acc)[4][4]) {
    #pragma unroll
    for (int mi = 0; mi < 4; mi++)
        #pragma unroll
        for (int ni = 0; ni < 4; ni++) {
            f32x4 z = {0.f, 0.f, 0.f, 0.f};
            acc[mi][ni] = z;
        }
    #pragma unroll
    for (int kc = 0; kc < KD8 / 4; kc++) {
        bf16x8 a[4], b[4];
        #pragma unroll
        for (int mi = 0; mi < 4; mi++)
            a[mi] = *(const bf16x8*)&P[((size_t)(rb16 + mi) * KD8 * 16
                                        + kc * 64 + lane) * 8];
        #pragma unroll
        for (int ni = 0; ni < 4; ni++)
            b[ni] = *(const bf16x8*)&P[((size_t)(cb16 + ni) * KD8 * 16
                                        + kc * 64 + lane) * 8];
        #pragma unroll
        for (int mi = 0; mi < 4; mi++)
            #pragma unroll
            for (int ni = 0; ni < 4; ni++)
                acc[mi][ni] = __builtin_amdgcn_mfma_f32_16x16x32_bf16(
                    a[mi], b[ni], acc[mi][ni], 0, 0, 0);
    }
}

// ---------------------------------------------------------------- stats ----
__global__ __launch_bounds__(256, 2) void stats_kernel(
    const short* __restrict__ Lnp, const short* __restrict__ Obp,
    const float* __restrict__ sq, unsigned* __restrict__ stats) {
    int bi, bj;
    tri_decode_swz(blockIdx.x, bi, bj);
    int tid = threadIdx.x, lane = tid & 63, wid = tid >> 6;
    int wm = (wid >> 1) * 64, wn = (wid & 1) * 64;
    int l15 = lane & 15, quad = lane >> 4;
    int rb16 = bi * 8 + (wid >> 1) * 4, cb16 = bj * 8 + (wid & 1) * 4;
    int rB = bi * TILE, cB = bj * TILE;

    float lmin = 1e30f, lmax = -1e30f, dmax = 0.f;
    f32x4 acc[4][4];

    gram_packed<16>(Lnp, rb16, cb16, lane, acc);
    #pragma unroll
    for (int mi = 0; mi < 4; mi++)
        #pragma unroll
        for (int ni = 0; ni < 4; ni++)
            #pragma unroll
            for (int r = 0; r < 4; r++) {
                float s = acc[mi][ni][r];
                lmin = fminf(lmin, s);
                lmax = fmaxf(lmax, s);
            }

    gram_packed<32>(Obp, rb16, cb16, lane, acc);
    float sqj[4];
    #pragma unroll
    for (int ni = 0; ni < 4; ni++) sqj[ni] = sq[cB + wn + ni * 16 + l15];
    #pragma unroll
    for (int mi = 0; mi < 4; mi++) {
        f32x4 sqi = *(const f32x4*)&sq[rB + wm + mi * 16 + quad * 4];
        #pragma unroll
        for (int r = 0; r < 4; r++)
            #pragma unroll
            for (int ni = 0; ni < 4; ni++) {
                float d2 = fmaxf(sqi[r] + sqj[ni] - 2.f * acc[mi][ni][r], 0.f);
                dmax = fmaxf(dmax, d2);
            }
    }

    #pragma unroll
    for (int m = 1; m < 64; m <<= 1) {
        lmin = fminf(lmin, __shfl_xor(lmin, m));
        lmax = fmaxf(lmax, __shfl_xor(lmax, m));
        dmax = fmaxf(dmax, __shfl_xor(dmax, m));
    }
    __shared__ float red[3][4];
    if ((tid & 63) == 0) { red[0][wid] = lmin; red[1][wid] = lmax; red[2][wid] = dmax; }
    __syncthreads();
    if (tid == 0) {
        lmin = fminf(fminf(red[0][0], red[0][1]), fminf(red[0][2], red[0][3]));
        lmax = fmaxf(fmaxf(red[1][0], red[1][1]), fmaxf(red[1][2], red[1][3]));
        dmax = fmaxf(fmaxf(red[2][0], red[2][1]), fmaxf(red[2][2], red[2][3]));
        atomicMin(&stats[0], fenc(lmin));
        atomicMax(&stats[1], fenc(lmax));
        atomicMax(&stats[2], fenc(dmax));
    }
}

// ----------------------------------------------------------------- loss ----
__global__ __launch_bounds__(256, 2) void loss_kernel(
    const short* __restrict__ Lnp, const short* __restrict__ Obp,
    const float* __restrict__ sq, const unsigned* __restrict__ stats,
    float* __restrict__ pos_sums, float* __restrict__ neg_sums) {
    int bi, bj;
    tri_decode_swz(blockIdx.x, bi, bj);
    int tid = threadIdx.x, lane = tid & 63, wid = tid >> 6;
    int wm = (wid >> 1) * 64, wn = (wid & 1) * 64;
    int l15 = lane & 15, quad = lane >> 4;
    int rb16 = bi * 8 + (wid >> 1) * 4, cb16 = bj * 8 + (wid & 1) * 4;
    int rB = bi * TILE, cB = bj * TILE;

    __shared__ float rP[TILE][2], rN[TILE][2];
    __shared__ float cP[TILE][2], cN[TILE][2];

    f32x4 acc[4][4];

    // --- sim gram; pack raw sim to f16 pairs in 32 regs ---
    gram_packed<16>(Lnp, rb16, cb16, lane, acc);
    unsigned sp[4][4][2];
    #pragma unroll
    for (int mi = 0; mi < 4; mi++)
        #pragma unroll
        for (int ni = 0; ni < 4; ni++) {
            sp[mi][ni][0] = pack2(acc[mi][ni][0], acc[mi][ni][1]);
            sp[mi][ni][1] = pack2(acc[mi][ni][2], acc[mi][ni][3]);
        }

    // --- outputs gram (reuses acc) ---
    gram_packed<32>(Obp, rb16, cb16, lane, acc);

    float smin = fdec(stats[0]);
    float smax = fdec(stats[1]);
    float d2max = fdec(stats[2]);
    float invr = 1.f / (smax - smin);
    float invem = rsqrtf(d2max);

    float sqj[4];
    #pragma unroll
    for (int ni = 0; ni < 4; ni++) sqj[ni] = sq[cB + wn + ni * 16 + l15];
    float cpsum[4] = {0.f, 0.f, 0.f, 0.f};
    float cnsum[4] = {0.f, 0.f, 0.f, 0.f};

    #pragma unroll
    for (int mi = 0; mi < 4; mi++) {
        f32x4 sqi = *(const f32x4*)&sq[rB + wm + mi * 16 + quad * 4];
        float ps[4] = {0.f, 0.f, 0.f, 0.f};
        float ns[4] = {0.f, 0.f, 0.f, 0.f};
        #pragma unroll
        for (int ni = 0; ni < 4; ni++) {
            f16x2 s01 = *(f16x2*)&sp[mi][ni][0];
            f16x2 s23 = *(f16x2*)&sp[mi][ni][1];
            #pragma unroll
            for (int r = 0; r < 4; r++) {
                float sraw = (r < 2) ? (float)s01[r] : (float)s23[r - 2];
                float sn = (sraw - smin) * invr;
                float g = acc[mi][ni][r];
                float d2 = fmaxf(sqi[r] + sqj[ni] - 2.f * g, 0.f);
                float eud = (d2 > 0.f) ? sqrtf(d2) * invem : 0.f;
                float dist = eud + sn;
                bool pos = sn > 0.5f;   // TAU
                float pv = pos ? __expf(dist) : 0.f;
                float nv = pos ? 0.f : __expf(1.0f - dist);  // MAG = 1
                ps[r] += pv;  ns[r] += nv;
                cpsum[ni] += pv;  cnsum[ni] += nv;
            }
        }
        #pragma unroll
        for (int r = 0; r < 4; r++) {
            #pragma unroll
            for (int m = 1; m < 16; m <<= 1) {
                ps[r] += __shfl_xor(ps[r], m);
                ns[r] += __shfl_xor(ns[r], m);
            }
            if (l15 == 0) {
                int rr = wm + mi * 16 + quad * 4 + r;
                rP[rr][wid & 1] = ps[r];
                rN[rr][wid & 1] = ns[r];
            }
        }
    }
    #pragma unroll
    for (int ni = 0; ni < 4; ni++) {
        #pragma unroll
        for (int m = 16; m < 64; m <<= 1) {
            cpsum[ni] += __shfl_xor(cpsum[ni], m);
            cnsum[ni] += __shfl_xor(cnsum[ni], m);
        }
        if (quad == 0) {
            int cc = wn + ni * 16 + l15;
            cP[cc][wid >> 1] = cpsum[ni];
            cN[cc][wid >> 1] = cnsum[ni];
        }
    }
    __syncthreads();
    if (tid < TILE) {
        atomicAdd(&pos_sums[bi * TILE + tid], rP[tid][0] + rP[tid][1]);
        atomicAdd(&neg_sums[bi * TILE + tid], rN[tid][0] + rN[tid][1]);
        if (bi != bj) {
            atomicAdd(&pos_sums[bj * TILE + tid], cP[tid][0] + cP[tid][1]);
            atomicAdd(&neg_sums[bj * TILE + tid], cN[tid][0] + cN[tid][1]);
        }
    }
}

// ------------------------------------------------------------- finalize ----
__global__ __launch_bounds__(256) void finalize_kernel(
    const float* __restrict__ pos_sums, const float* __restrict__ neg_sums,
    float* __restrict__ out) {
    int t = threadIdx.x;
    float acc = 0.f;
    for (int i = t; i < B_N; i += 256) {
        float p = pos_sums[i], n = neg_sums[i];
        float pl = fmaxf(logf(p), 0.f);
        float nl = (n > 0.f) ? fmaxf(logf(n), 0.f) : 0.f;
        acc += pl + nl;
    }
    #pragma unroll
    for (int m = 1; m < 64; m <<= 1) acc += __shfl_xor(acc, m);
    __shared__ float w4[4];
    if ((t & 63) == 0) w4[t >> 6] = acc;
    __syncthreads();
    if (t == 0) out[0] = (w4[0] + w4[1] + w4[2] + w4[3]) / (float)B_N;
}

// ------------------------------------------------------------------ entry ----
extern "C" void kernel_launch(void* const* d_in, const int* in_sizes, int n_in,
                              void* d_out, int out_size, void* d_ws, size_t ws_size,
                              hipStream_t stream) {
    const float* outputs = (const float*)d_in[0];
    const float* labels  = (const float*)d_in[1];
    float* out = (float*)d_out;
    char* ws = (char*)d_ws;
    __hip_bfloat16* Obp = (__hip_bfloat16*)(ws);
    __hip_bfloat16* Lnp = (__hip_bfloat16*)(ws + 4194304);
    float* sq           = (float*)(ws + 6291456);
    float* pos_sums     = (float*)(ws + 6324224);
    float* neg_sums     = (float*)(ws + 6356992);
    unsigned* stats     = (unsigned*)(ws + 6389760);

    prep_kernel<<<B_N / 4, 256, 0, stream>>>(outputs, labels, Obp, Lnp, sq,
                                             pos_sums, neg_sums, stats);
    stats_kernel<<<NTRI, 256, 0, stream>>>((const short*)Lnp, (const short*)Obp,
                                           sq, stats);
    loss_kernel<<<NTRI, 256, 0, stream>>>((const short*)Lnp, (const short*)Obp,
                                          sq, stats, pos_sums, neg_sums);
    finalize_kernel<<<1, 256, 0, stream>>>(pos_sums, neg_sums, out);
}

// Round 12
// 250.309 us; speedup vs baseline: 1.0033x; 1.0033x over previous
//
#include <hip/hip_runtime.h>
#include <hip/hip_bf16.h>

// WeightedLoss round 12: packed-fragment grams (r11) with the scratch-spill
// bug fixed. r11's loss wrote 64 MB of scratch: `*(f16x2*)&sp[...]` took the
// address of the per-thread sim cache and defeated mem2reg (2080*256*128 B
// = 68 MB = observed WRITE_SIZE). sp is now a typed f16x2 array accessed only
// with constant indices -> promoted to 32 VGPRs. stats gets (256,3) for
// 3 waves/SIMD latency hiding (no sp array; ~130 live regs fits 170 cap).
// ws: [0] Obp bf16 packed 4 MB | [4194304] Lnp bf16 packed 2 MB
//     [6291456] sq f32 | [6324224] pos_sums | [6356992] neg_sums
//     [6389760] stats u32[3]

#define B_N 8192
#define NT   64
#define TILE 128
#define NTRI 2080

typedef __attribute__((ext_vector_type(8))) short bf16x8;
typedef __attribute__((ext_vector_type(4))) float f32x4;
typedef __attribute__((ext_vector_type(2))) _Float16 f16x2;

__device__ __forceinline__ unsigned fenc(float f) {
    unsigned u = __float_as_uint(f);
    return (u & 0x80000000u) ? ~u : (u | 0x80000000u);
}
__device__ __forceinline__ float fdec(unsigned k) {
    unsigned u = (k & 0x80000000u) ? (k ^ 0x80000000u) : ~k;
    return __uint_as_float(u);
}

// XCD-swizzled upper-tri decode.
__device__ __forceinline__ void tri_decode_swz(int b, int& bi, int& bj) {
    int t = (b & 7) * (NTRI / 8) + (b >> 3);
    int i = 0, rem = t;
    while (rem >= NT - i) { rem -= NT - i; i++; }
    bi = i; bj = i + rem;
}

// ---------------------------------------------------------------- prep ----
// 4 rows/block (one wave per row). Computes sq, normalizes labels, writes
// both matrices in packed fragment order: 16-B slot S=(g*(K/8)+o)*16+r holds
// X[g*16+r][o*8..o*8+7].
__global__ __launch_bounds__(256) void prep_kernel(
    const float* __restrict__ outputs, const float* __restrict__ labels,
    __hip_bfloat16* __restrict__ Obp, __hip_bfloat16* __restrict__ Lnp,
    float* __restrict__ sq, float* __restrict__ pos_sums,
    float* __restrict__ neg_sums, unsigned* __restrict__ stats) {
    int w = threadIdx.x >> 6, lane = threadIdx.x & 63;
    int r = blockIdx.x * 4 + w;
    int g = r >> 4, rr = r & 15;

    f32x4 v = ((const f32x4*)outputs)[r * 64 + lane];
    float s = v[0]*v[0] + v[1]*v[1] + v[2]*v[2] + v[3]*v[3];
    #pragma unroll
    for (int m = 1; m < 64; m <<= 1) s += __shfl_xor(s, m);
    if (lane == 0) { sq[r] = s; pos_sums[r] = 0.f; neg_sums[r] = 0.f; }
    __hip_bfloat16 o4[4];
    #pragma unroll
    for (int i = 0; i < 4; i++) o4[i] = __float2bfloat16(v[i]);
    {   // elems 4*lane.. -> octet o=lane>>1, pos=4*(lane&1); K/8=32
        int o = lane >> 1, pos = 4 * (lane & 1);
        size_t S = ((size_t)g * 32 + o) * 16 + rr;
        *(uint2*)&Obp[S * 8 + pos] = *(uint2*)o4;
    }

    float2 lv = ((const float2*)labels)[r * 64 + lane];
    float ls = lv.x * lv.x + lv.y * lv.y;
    #pragma unroll
    for (int m = 1; m < 64; m <<= 1) ls += __shfl_xor(ls, m);
    float nrm = sqrtf(ls) + 1e-12f;
    __hip_bfloat16 l2[2] = { __float2bfloat16(lv.x / nrm),
                             __float2bfloat16(lv.y / nrm) };
    {   // elems 2*lane.. -> octet o=lane>>2, pos=2*(lane&3); K/8=16
        int o = lane >> 2, pos = 2 * (lane & 3);
        size_t S = ((size_t)g * 16 + o) * 16 + rr;
        *(unsigned*)&Lnp[S * 8 + pos] = *(unsigned*)l2;
    }

    if (blockIdx.x == 0 && threadIdx.x == 0) {
        stats[0] = 0xFFFFFFFFu; stats[1] = 0u; stats[2] = 0u;
    }
}

// ------------------------------------ packed direct-global 64x64 gram ----
template<int KD8>
__device__ __forceinline__ void gram_packed(
    const short* __restrict__ P, int rb16, int cb16, int lane,
    f32x4 (&acc)[4][4]) {
    #pragma unroll
    for (int mi = 0; mi < 4; mi++)
        #pragma unroll
        for (int ni = 0; ni < 4; ni++) {
            f32x4 z = {0.f, 0.f, 0.f, 0.f};
            acc[mi][ni] = z;
        }
    #pragma unroll
    for (int kc = 0; kc < KD8 / 4; kc++) {
        bf16x8 a[4], b[4];
        #pragma unroll
        for (int mi = 0; mi < 4; mi++)
            a[mi] = *(const bf16x8*)&P[((size_t)(rb16 + mi) * KD8 * 16
                                        + kc * 64 + lane) * 8];
        #pragma unroll
        for (int ni = 0; ni < 4; ni++)
            b[ni] = *(const bf16x8*)&P[((size_t)(cb16 + ni) * KD8 * 16
                                        + kc * 64 + lane) * 8];
        #pragma unroll
        for (int mi = 0; mi < 4; mi++)
            #pragma unroll
            for (int ni = 0; ni < 4; ni++)
                acc[mi][ni] = __builtin_amdgcn_mfma_f32_16x16x32_bf16(
                    a[mi], b[ni], acc[mi][ni], 0, 0, 0);
    }
}

// ---------------------------------------------------------------- stats ----
__global__ __launch_bounds__(256, 3) void stats_kernel(
    const short* __restrict__ Lnp, const short* __restrict__ Obp,
    const float* __restrict__ sq, unsigned* __restrict__ stats) {
    int bi, bj;
    tri_decode_swz(blockIdx.x, bi, bj);
    int tid = threadIdx.x, lane = tid & 63, wid = tid >> 6;
    int wm = (wid >> 1) * 64, wn = (wid & 1) * 64;
    int l15 = lane & 15, quad = lane >> 4;
    int rb16 = bi * 8 + (wid >> 1) * 4, cb16 = bj * 8 + (wid & 1) * 4;
    int rB = bi * TILE, cB = bj * TILE;

    float lmin = 1e30f, lmax = -1e30f, dmax = 0.f;
    f32x4 acc[4][4];

    gram_packed<16>(Lnp, rb16, cb16, lane, acc);
    #pragma unroll
    for (int mi = 0; mi < 4; mi++)
        #pragma unroll
        for (int ni = 0; ni < 4; ni++)
            #pragma unroll
            for (int r = 0; r < 4; r++) {
                float s = acc[mi][ni][r];
                lmin = fminf(lmin, s);
                lmax = fmaxf(lmax, s);
            }

    gram_packed<32>(Obp, rb16, cb16, lane, acc);
    float sqj[4];
    #pragma unroll
    for (int ni = 0; ni < 4; ni++) sqj[ni] = sq[cB + wn + ni * 16 + l15];
    #pragma unroll
    for (int mi = 0; mi < 4; mi++) {
        f32x4 sqi = *(const f32x4*)&sq[rB + wm + mi * 16 + quad * 4];
        #pragma unroll
        for (int r = 0; r < 4; r++)
            #pragma unroll
            for (int ni = 0; ni < 4; ni++) {
                float d2 = fmaxf(sqi[r] + sqj[ni] - 2.f * acc[mi][ni][r], 0.f);
                dmax = fmaxf(dmax, d2);
            }
    }

    #pragma unroll
    for (int m = 1; m < 64; m <<= 1) {
        lmin = fminf(lmin, __shfl_xor(lmin, m));
        lmax = fmaxf(lmax, __shfl_xor(lmax, m));
        dmax = fmaxf(dmax, __shfl_xor(dmax, m));
    }
    __shared__ float red[3][4];
    if ((tid & 63) == 0) { red[0][wid] = lmin; red[1][wid] = lmax; red[2][wid] = dmax; }
    __syncthreads();
    if (tid == 0) {
        lmin = fminf(fminf(red[0][0], red[0][1]), fminf(red[0][2], red[0][3]));
        lmax = fmaxf(fmaxf(red[1][0], red[1][1]), fmaxf(red[1][2], red[1][3]));
        dmax = fmaxf(fmaxf(red[2][0], red[2][1]), fmaxf(red[2][2], red[2][3]));
        atomicMin(&stats[0], fenc(lmin));
        atomicMax(&stats[1], fenc(lmax));
        atomicMax(&stats[2], fenc(dmax));
    }
}

// ----------------------------------------------------------------- loss ----
__global__ __launch_bounds__(256, 2) void loss_kernel(
    const short* __restrict__ Lnp, const short* __restrict__ Obp,
    const float* __restrict__ sq, const unsigned* __restrict__ stats,
    float* __restrict__ pos_sums, float* __restrict__ neg_sums) {
    int bi, bj;
    tri_decode_swz(blockIdx.x, bi, bj);
    int tid = threadIdx.x, lane = tid & 63, wid = tid >> 6;
    int wm = (wid >> 1) * 64, wn = (wid & 1) * 64;
    int l15 = lane & 15, quad = lane >> 4;
    int rb16 = bi * 8 + (wid >> 1) * 4, cb16 = bj * 8 + (wid & 1) * 4;
    int rB = bi * TILE, cB = bj * TILE;

    __shared__ float rP[TILE][2], rN[TILE][2];
    __shared__ float cP[TILE][2], cN[TILE][2];

    f32x4 acc[4][4];

    // --- sim gram; cache raw sim as typed f16 pairs (NO address casts ->
    //     promotable to 32 VGPRs; r11's cast spilled 68 MB to scratch) ---
    gram_packed<16>(Lnp, rb16, cb16, lane, acc);
    f16x2 sp[4][4][2];
    #pragma unroll
    for (int mi = 0; mi < 4; mi++)
        #pragma unroll
        for (int ni = 0; ni < 4; ni++)
            #pragma unroll
            for (int p = 0; p < 2; p++) {
                f16x2 t;
                t[0] = (_Float16)acc[mi][ni][2 * p];
                t[1] = (_Float16)acc[mi][ni][2 * p + 1];
                sp[mi][ni][p] = t;
            }

    // --- outputs gram (reuses acc) ---
    gram_packed<32>(Obp, rb16, cb16, lane, acc);

    float smin = fdec(stats[0]);
    float smax = fdec(stats[1]);
    float d2max = fdec(stats[2]);
    float invr = 1.f / (smax - smin);
    float invem = rsqrtf(d2max);

    float sqj[4];
    #pragma unroll
    for (int ni = 0; ni < 4; ni++) sqj[ni] = sq[cB + wn + ni * 16 + l15];
    float cpsum[4] = {0.f, 0.f, 0.f, 0.f};
    float cnsum[4] = {0.f, 0.f, 0.f, 0.f};

    #pragma unroll
    for (int mi = 0; mi < 4; mi++) {
        f32x4 sqi = *(const f32x4*)&sq[rB + wm + mi * 16 + quad * 4];
        float ps[4] = {0.f, 0.f, 0.f, 0.f};
        float ns[4] = {0.f, 0.f, 0.f, 0.f};
        #pragma unroll
        for (int ni = 0; ni < 4; ni++) {
            #pragma unroll
            for (int r = 0; r < 4; r++) {
                float sraw = (float)sp[mi][ni][r >> 1][r & 1];
                float sn = (sraw - smin) * invr;
                float g = acc[mi][ni][r];
                float d2 = fmaxf(sqi[r] + sqj[ni] - 2.f * g, 0.f);
                float eud = (d2 > 0.f) ? sqrtf(d2) * invem : 0.f;
                float dist = eud + sn;
                bool pos = sn > 0.5f;   // TAU
                float pv = pos ? __expf(dist) : 0.f;
                float nv = pos ? 0.f : __expf(1.0f - dist);  // MAG = 1
                ps[r] += pv;  ns[r] += nv;
                cpsum[ni] += pv;  cnsum[ni] += nv;
            }
        }
        #pragma unroll
        for (int r = 0; r < 4; r++) {
            #pragma unroll
            for (int m = 1; m < 16; m <<= 1) {
                ps[r] += __shfl_xor(ps[r], m);
                ns[r] += __shfl_xor(ns[r], m);
            }
            if (l15 == 0) {
                int rr = wm + mi * 16 + quad * 4 + r;
                rP[rr][wid & 1] = ps[r];
                rN[rr][wid & 1] = ns[r];
            }
        }
    }
    #pragma unroll
    for (int ni = 0; ni < 4; ni++) {
        #pragma unroll
        for (int m = 16; m < 64; m <<= 1) {
            cpsum[ni] += __shfl_xor(cpsum[ni], m);
            cnsum[ni] += __shfl_xor(cnsum[ni], m);
        }
        if (quad == 0) {
            int cc = wn + ni * 16 + l15;
            cP[cc][wid >> 1] = cpsum[ni];
            cN[cc][wid >> 1] = cnsum[ni];
        }
    }
    __syncthreads();
    if (tid < TILE) {
        atomicAdd(&pos_sums[bi * TILE + tid], rP[tid][0] + rP[tid][1]);
        atomicAdd(&neg_sums[bi * TILE + tid], rN[tid][0] + rN[tid][1]);
        if (bi != bj) {
            atomicAdd(&pos_sums[bj * TILE + tid], cP[tid][0] + cP[tid][1]);
            atomicAdd(&neg_sums[bj * TILE + tid], cN[tid][0] + cN[tid][1]);
        }
    }
}

// ------------------------------------------------------------- finalize ----
__global__ __launch_bounds__(256) void finalize_kernel(
    const float* __restrict__ pos_sums, const float* __restrict__ neg_sums,
    float* __restrict__ out) {
    int t = threadIdx.x;
    float acc = 0.f;
    for (int i = t; i < B_N; i += 256) {
        float p = pos_sums[i], n = neg_sums[i];
        float pl = fmaxf(logf(p), 0.f);
        float nl = (n > 0.f) ? fmaxf(logf(n), 0.f) : 0.f;
        acc += pl + nl;
    }
    #pragma unroll
    for (int m = 1; m < 64; m <<= 1) acc += __shfl_xor(acc, m);
    __shared__ float w4[4];
    if ((t & 63) == 0) w4[t >> 6] = acc;
    __syncthreads();
    if (t == 0) out[0] = (w4[0] + w4[1] + w4[2] + w4[3]) / (float)B_N;
}

// ------------------------------------------------------------------ entry ----
extern "C" void kernel_launch(void* const* d_in, const int* in_sizes, int n_in,
                              void* d_out, int out_size, void* d_ws, size_t ws_size,
                              hipStream_t stream) {
    const float* outputs = (const float*)d_in[0];
    const float* labels  = (const float*)d_in[1];
    float* out = (float*)d_out;
    char* ws = (char*)d_ws;
    __hip_bfloat16* Obp = (__hip_bfloat16*)(ws);
    __hip_bfloat16* Lnp = (__hip_bfloat16*)(ws + 4194304);
    float* sq           = (float*)(ws + 6291456);
    float* pos_sums     = (float*)(ws + 6324224);
    float* neg_sums     = (float*)(ws + 6356992);
    unsigned* stats     = (unsigned*)(ws + 6389760);

    prep_kernel<<<B_N / 4, 256, 0, stream>>>(outputs, labels, Obp, Lnp, sq,
                                             pos_sums, neg_sums, stats);
    stats_kernel<<<NTRI, 256, 0, stream>>>((const short*)Lnp, (const short*)Obp,
                                           sq, stats);
    loss_kernel<<<NTRI, 256, 0, stream>>>((const short*)Lnp, (const short*)Obp,
                                          sq, stats, pos_sums, neg_sums);
    finalize_kernel<<<1, 256, 0, stream>>>(pos_sums, neg_sums, out);
}